// Round 1
// 495.949 us; speedup vs baseline: 1.2153x; 1.2153x over previous
//
#include <hip/hip_runtime.h>
#include <math.h>

#define B_   4
#define S_   4096
#define IN_  4096
#define OUT_ 4096
#define RNK  8
#define K_   4

#define HALFC 2048          // columns per kA block (2 halves)
#define NKCH  8             // 2048 / 256 column chunks per block

typedef float f4v __attribute__((ext_vector_type(4)));

// ---------------------------------------------------------------------------
// zK: zero the global colsum accumulator (d_ws is poisoned every call).
// ---------------------------------------------------------------------------
__global__ __launch_bounds__(256) void zK(float* __restrict__ p) {
    p[blockIdx.x * 256 + threadIdx.x] = 0.f;
}

// ---------------------------------------------------------------------------
// Kernel A (restructured): grid = B * 128 sblk * 2 column-halves = 1024.
// Block: 512 threads = 8 waves; wave w owns rows s0..s0+3, all 2048 cols of
// its half in 8 chunks of 256 (lane l -> cols l*4..l*4+3).
//  - V half-slice staged once in LDS (64 KB) -> V reads off the vmcnt path.
//  - 4 independent x float4 loads per chunk (one per row), unroll 2.
//  - colsum: reduced over the 4 rows IN REGISTERS, then 4 conflict-free LDS
//    atomics per chunk into component-major shcs[4][512] (lane-stride-1).
//  - dot products: acc[4][8] in registers, ONE 64-lane butterfly at the end.
//  - xv written as per-half partials; kD sums the two halves.
// ---------------------------------------------------------------------------
__global__ __launch_bounds__(512, 4) void kA(const float* __restrict__ x,
                                             const float* __restrict__ V,
                                             float* __restrict__ colsum, // [B_][IN_]
                                             float* __restrict__ xvp)    // [2][B_][S_][RNK]
{
    __shared__ float Vsh[RNK][HALFC];   // 64 KB
    __shared__ float shcs[4][512];      // 8 KB; shcs[comp][k*64+l] = col k*256+l*4+comp
    const int tid = threadIdx.x;

    const int blk  = blockIdx.x;        // 1024 = B * 128 * 2
    const int b    = blk >> 8;
    const int rem  = blk & 255;
    const int sblk = rem >> 1;
    const int half = rem & 1;
    const int c0   = half * HALFC;

    // zero block colsum
    for (int i = tid; i < 2048; i += 512) ((float*)shcs)[i] = 0.f;

    // stage V half-slice: 8 rows x 2048 cols = 4096 float4s
    for (int i = tid; i < (RNK * HALFC / 4); i += 512) {
        const int r  = i >> 9;                 // 512 float4 per row
        const int cc = (i & 511) * 4;
        *(float4*)&Vsh[r][cc] = *(const float4*)(V + (size_t)r * IN_ + c0 + cc);
    }
    __syncthreads();

    const int w = tid >> 6, l = tid & 63;
    const int s0 = sblk * 32 + w * 4;
    const float* xb = x + ((size_t)(b * S_ + s0)) * IN_ + c0 + l * 4;

    float acc[4][8];
    #pragma unroll
    for (int row = 0; row < 4; ++row)
        #pragma unroll
        for (int r = 0; r < 8; ++r) acc[row][r] = 0.f;

    #pragma unroll 2
    for (int k = 0; k < NKCH; ++k) {
        const int col = k * 256 + l * 4;
        float4 xr[4];
        #pragma unroll
        for (int row = 0; row < 4; ++row)
            xr[row] = *(const float4*)(xb + (size_t)row * IN_ + k * 256);
        float4 vr[8];
        #pragma unroll
        for (int r = 0; r < 8; ++r) vr[r] = *(const float4*)&Vsh[r][col];

        #pragma unroll
        for (int row = 0; row < 4; ++row) {
            #pragma unroll
            for (int r = 0; r < 8; ++r)
                acc[row][r] += xr[row].x * vr[r].x + xr[row].y * vr[r].y
                             + xr[row].z * vr[r].z + xr[row].w * vr[r].w;
        }

        // column sums over the wave's 4 rows, in registers
        const float c0s = xr[0].x + xr[1].x + xr[2].x + xr[3].x;
        const float c1s = xr[0].y + xr[1].y + xr[2].y + xr[3].y;
        const float c2s = xr[0].z + xr[1].z + xr[2].z + xr[3].z;
        const float c3s = xr[0].w + xr[1].w + xr[2].w + xr[3].w;
        const int q = k * 64 + l;                 // lane-stride-1 -> 2-way banks (free)
        atomicAdd(&shcs[0][q], c0s);
        atomicAdd(&shcs[1][q], c1s);
        atomicAdd(&shcs[2][q], c2s);
        atomicAdd(&shcs[3][q], c3s);
    }

    // full-wave butterfly: every lane ends with the total dot for its rows
    #pragma unroll
    for (int m = 1; m <= 32; m <<= 1)
        #pragma unroll
        for (int row = 0; row < 4; ++row)
            #pragma unroll
            for (int r = 0; r < 8; ++r)
                acc[row][r] += __shfl_xor(acc[row][r], m);

    if (l == 0) {
        float* xo = xvp + (size_t)half * (B_ * S_ * RNK)
                        + ((size_t)(b * S_ + s0)) * RNK;
        #pragma unroll
        for (int row = 0; row < 4; ++row) {
            *(float4*)(xo + row * RNK)     = make_float4(acc[row][0], acc[row][1],
                                                         acc[row][2], acc[row][3]);
            *(float4*)(xo + row * RNK + 4) = make_float4(acc[row][4], acc[row][5],
                                                         acc[row][6], acc[row][7]);
        }
    }

    __syncthreads();
    // flush per-block colsum into the global accumulator (fire-and-forget)
    for (int i = tid; i < 2048; i += 512) {
        const int comp = i >> 9, q = i & 511;
        unsafeAtomicAdd(&colsum[(size_t)b * IN_ + c0 + q * 4 + comp], ((float*)shcs)[i]);
    }
}

// ---------------------------------------------------------------------------
// Kernel B: one block per batch b, now 1024 threads (16 waves) to cut the
// latency exposure of this 4-block kernel 4x. colsum already reduced ->
// centroid, cosine router + softmax(T=0.05), gate, Lam mixture, then
// P[b,o,r] = gate * sum_j U[o,j] * Lam[b,j,r].
// ---------------------------------------------------------------------------
__global__ __launch_bounds__(1024) void kB(const float* __restrict__ x,
                                           const float* __restrict__ V,
                                           const float* __restrict__ U,
                                           const float* __restrict__ core_pool,
                                           const float* __restrict__ core_keys,
                                           const float* __restrict__ gate_w,
                                           const float* __restrict__ gate_b,
                                           const float* __restrict__ colsum,
                                           float* __restrict__ P) // [B_][OUT_][RNK]
{
    const int b = blockIdx.x, tid = threadIdx.x;
    float nrm2 = 0.f;
    float dotk[K_] = {0.f,0.f,0.f,0.f};
    float kn2[K_]  = {0.f,0.f,0.f,0.f};
    float us[8] = {0.f,0.f,0.f,0.f,0.f,0.f,0.f,0.f};
    float vs[8] = {0.f,0.f,0.f,0.f,0.f,0.f,0.f,0.f};

    const float ms = 0.3f / (float)S_;
    {
        const int c = tid * 4;   // 1024 threads x 4 = 4096 cols, single pass
        const float4 cs = *(const float4*)(colsum + (size_t)b * IN_ + c);
        const float4 xl = *(const float4*)(x + ((size_t)(b * S_ + S_ - 1)) * IN_ + c);
        float4 cen;
        cen.x = 0.7f * xl.x + ms * cs.x;
        cen.y = 0.7f * xl.y + ms * cs.y;
        cen.z = 0.7f * xl.z + ms * cs.z;
        cen.w = 0.7f * xl.w + ms * cs.w;
        nrm2 += cen.x*cen.x + cen.y*cen.y + cen.z*cen.z + cen.w*cen.w;
        #pragma unroll
        for (int k = 0; k < K_; ++k) {
            const float4 ck = *(const float4*)(core_keys + (size_t)k * IN_ + c);
            dotk[k] += cen.x*ck.x + cen.y*ck.y + cen.z*ck.z + cen.w*ck.w;
            kn2[k]  += ck.x*ck.x + ck.y*ck.y + ck.z*ck.z + ck.w*ck.w;
        }
    }
    for (int o = tid; o < OUT_; o += 1024) {
        const float4 a  = *(const float4*)(U + (size_t)o * RNK);
        const float4 b4 = *(const float4*)(U + (size_t)o * RNK + 4);
        us[0]+=a.x;  us[1]+=a.y;  us[2]+=a.z;  us[3]+=a.w;
        us[4]+=b4.x; us[5]+=b4.y; us[6]+=b4.z; us[7]+=b4.w;
    }
    {
        const int c = tid * 4;
        #pragma unroll
        for (int r = 0; r < 8; ++r) {
            const float4 v = *(const float4*)(V + (size_t)r * IN_ + c);
            vs[r] += v.x + v.y + v.z + v.w;
        }
    }

    // block-reduce 25 scalars: wave shuffle then cross-wave via LDS (16 waves)
    __shared__ float red[25 * 16];
    __shared__ float res[25];
    float vals[25];
    vals[0] = nrm2;
    #pragma unroll
    for (int k = 0; k < K_; ++k) { vals[1 + k] = dotk[k]; vals[5 + k] = kn2[k]; }
    #pragma unroll
    for (int r = 0; r < 8; ++r) { vals[9 + r] = us[r]; vals[17 + r] = vs[r]; }
    const int wid = tid >> 6, lane = tid & 63;
    #pragma unroll
    for (int i = 0; i < 25; ++i) {
        float v = vals[i];
        #pragma unroll
        for (int m = 32; m >= 1; m >>= 1) v += __shfl_xor(v, m);
        if (lane == 0) red[i * 16 + wid] = v;
    }
    __syncthreads();
    if (tid < 25) {
        float t = 0.f;
        #pragma unroll
        for (int j = 0; j < 16; ++j) t += red[tid * 16 + j];
        res[tid] = t;
    }
    __syncthreads();

    // router scalars (computed redundantly by every thread)
    const float ncen = fmaxf(sqrtf(res[0]), 1e-8f);
    float lg[K_], mx = -1e30f;
    #pragma unroll
    for (int k = 0; k < K_; ++k) {
        const float nk = fmaxf(sqrtf(res[5 + k]), 1e-8f);
        lg[k] = (res[1 + k] / (ncen * nk)) * 20.0f;   // /TEMP, TEMP=0.05
        mx = fmaxf(mx, lg[k]);
    }
    float wk[K_], se = 0.f;
    #pragma unroll
    for (int k = 0; k < K_; ++k) { wk[k] = expf(lg[k] - mx); se += wk[k]; }
    const float inv_se = 1.f / se;
    float z = gate_b[0];
    #pragma unroll
    for (int r = 0; r < 8; ++r) z += gate_w[r]     * (res[9 + r]  * (1.f / OUT_));
    #pragma unroll
    for (int r = 0; r < 8; ++r) z += gate_w[8 + r] * (res[17 + r] * (1.f / IN_));
    const float gate = 1.f / (1.f + expf(-z));

    __shared__ float Tsh[64];   // Tsh[j*8+r] = gate * Lam[b,j,r]
    if (tid < 64) {
        float acc = 0.f;
        #pragma unroll
        for (int k = 0; k < K_; ++k) acc += (wk[k] * inv_se) * core_pool[k * 64 + tid];
        Tsh[tid] = gate * acc;
    }
    __syncthreads();

    for (int o = tid; o < OUT_; o += 1024) {
        const float4 a  = *(const float4*)(U + (size_t)o * RNK);
        const float4 b4 = *(const float4*)(U + (size_t)o * RNK + 4);
        const float u[8] = {a.x, a.y, a.z, a.w, b4.x, b4.y, b4.z, b4.w};
        float pr[8];
        #pragma unroll
        for (int r = 0; r < 8; ++r) {
            float acc = 0.f;
            #pragma unroll
            for (int jj = 0; jj < 8; ++jj) acc += u[jj] * Tsh[jj * 8 + r];
            pr[r] = acc;
        }
        *(float4*)(P + (size_t)(b * OUT_ + o) * RNK)     = make_float4(pr[0], pr[1], pr[2], pr[3]);
        *(float4*)(P + (size_t)(b * OUT_ + o) * RNK + 4) = make_float4(pr[4], pr[5], pr[6], pr[7]);
    }
}

// ---------------------------------------------------------------------------
// Kernel D: out[b,s,o] = sum_r P[b,o,r] * (xv0+xv1)[b,s,r].  Write-bound.
// Non-temporal stores: keep the 256 MB `out` stream out of L3 so x stays
// L3-resident for the next iteration's kA.
// ---------------------------------------------------------------------------
__global__ __launch_bounds__(256) void kD(const float* __restrict__ P,
                                          const float* __restrict__ xv, // [2][B_][S_][RNK]
                                          float* __restrict__ out)
{
    const int blk = blockIdx.x;            // 2048 = B * 256 * 2
    const int b = blk >> 9, rem = blk & 511;
    const int half = rem >> 8, sc = rem & 255;
    const int t = threadIdx.x;
    const int oA = half * 2048 + t * 4;

    float PA[4][8], PB[4][8];
    #pragma unroll
    for (int u = 0; u < 4; ++u) {
        const float* pp = P + ((size_t)(b * OUT_ + oA + u)) * RNK;
        const float4 a = *(const float4*)pp;
        const float4 c = *(const float4*)(pp + 4);
        PA[u][0]=a.x; PA[u][1]=a.y; PA[u][2]=a.z; PA[u][3]=a.w;
        PA[u][4]=c.x; PA[u][5]=c.y; PA[u][6]=c.z; PA[u][7]=c.w;
        const float* pq = pp + (size_t)1024 * RNK;
        const float4 d = *(const float4*)pq;
        const float4 e = *(const float4*)(pq + 4);
        PB[u][0]=d.x; PB[u][1]=d.y; PB[u][2]=d.z; PB[u][3]=d.w;
        PB[u][4]=e.x; PB[u][5]=e.y; PB[u][6]=e.z; PB[u][7]=e.w;
    }

    const int srow0 = sc * 16;
    const float* xq0 = xv + ((size_t)(b * S_ + srow0)) * RNK;
    const float* xq1 = xq0 + (size_t)(B_ * S_ * RNK);
    float* op = out + ((size_t)(b * S_ + srow0)) * OUT_ + oA;
    #pragma unroll 4
    for (int row = 0; row < 16; ++row) {
        const float4 xa = *(const float4*)(xq0 + row * RNK);
        const float4 xb = *(const float4*)(xq0 + row * RNK + 4);
        const float4 ya = *(const float4*)(xq1 + row * RNK);
        const float4 yb = *(const float4*)(xq1 + row * RNK + 4);
        const float xr[8] = {xa.x+ya.x, xa.y+ya.y, xa.z+ya.z, xa.w+ya.w,
                             xb.x+yb.x, xb.y+yb.y, xb.z+yb.z, xb.w+yb.w};
        float accA[4], accB[4];
        #pragma unroll
        for (int u = 0; u < 4; ++u) {
            float sA = 0.f, sB = 0.f;
            #pragma unroll
            for (int r = 0; r < 8; ++r) { sA += PA[u][r] * xr[r]; sB += PB[u][r] * xr[r]; }
            accA[u] = sA; accB[u] = sB;
        }
        f4v vA = {accA[0], accA[1], accA[2], accA[3]};
        f4v vB = {accB[0], accB[1], accB[2], accB[3]};
        __builtin_nontemporal_store(vA, (f4v*)(op + (size_t)row * OUT_));
        __builtin_nontemporal_store(vB, (f4v*)(op + (size_t)row * OUT_ + 1024));
    }
}

extern "C" void kernel_launch(void* const* d_in, const int* in_sizes, int n_in,
                              void* d_out, int out_size, void* d_ws, size_t ws_size,
                              hipStream_t stream) {
    const float* x         = (const float*)d_in[0];
    const float* V         = (const float*)d_in[1];
    const float* U         = (const float*)d_in[2];
    const float* core_pool = (const float*)d_in[3];
    const float* core_keys = (const float*)d_in[4];
    const float* gate_w    = (const float*)d_in[5];
    const float* gate_b    = (const float*)d_in[6];
    float* out = (float*)d_out;

    // workspace: colsum [B,IN] + xv partials [2,B,S,8] + P [B,OUT,8] (~1.6 MB)
    float* colsum = (float*)d_ws;
    float* xv = colsum + (size_t)B_ * IN_;
    float* P  = xv + (size_t)2 * B_ * S_ * RNK;

    zK<<<dim3((B_ * IN_) / 256), dim3(256), 0, stream>>>(colsum);
    kA<<<dim3(1024), dim3(512), 0, stream>>>(x, V, colsum, xv);
    kB<<<dim3(B_), dim3(1024), 0, stream>>>(x, V, U, core_pool, core_keys,
                                            gate_w, gate_b, colsum, P);
    kD<<<dim3(2048), dim3(256), 0, stream>>>(P, xv, out);
}

// Round 2
// 495.695 us; speedup vs baseline: 1.2159x; 1.0005x over previous
//
#include <hip/hip_runtime.h>
#include <math.h>

#define B_   4
#define S_   4096
#define IN_  4096
#define OUT_ 4096
#define RNK  8
#define K_   4

#define HALFC 2048          // columns per kA block (2 halves)
#define NKCH  8             // 2048 / 256 column chunks per block

typedef float f4v __attribute__((ext_vector_type(4)));

// ---------------------------------------------------------------------------
// zK: zero the global colsum accumulator (d_ws is poisoned every call).
// ---------------------------------------------------------------------------
__global__ __launch_bounds__(256) void zK(float* __restrict__ p) {
    p[blockIdx.x * 256 + threadIdx.x] = 0.f;
}

// ---------------------------------------------------------------------------
// Kernel A: grid = B * 128 sblk * 2 column-halves = 1024 blocks, 512 thr.
// Wave w owns rows s0..s0+3 over its 2048-col half in 8 chunks of 256.
//  - V half staged once in LDS (64 KB).
//  - explicit 1-deep software pipeline on the 4 x row-loads (prefetch next
//    chunk into xn while FMA-ing xr) -> ~116 VGPR, fits the 128 cap of
//    __launch_bounds__(512,4) (2 blocks/CU, 16 waves) without spill.
//  - colsum reduced over the 4 rows in registers, 4 conflict-free LDS
//    atomics per chunk, one global unsafeAtomicAdd flush at the end.
//  - one 64-lane butterfly at kernel end; xv written as per-half partials.
// ---------------------------------------------------------------------------
__global__ __launch_bounds__(512, 4) void kA(const float* __restrict__ x,
                                             const float* __restrict__ V,
                                             float* __restrict__ colsum, // [B_][IN_]
                                             float* __restrict__ xvp)    // [2][B_][S_][RNK]
{
    __shared__ float Vsh[RNK][HALFC];   // 64 KB
    __shared__ float shcs[4][512];      // 8 KB; shcs[comp][k*64+l]
    const int tid = threadIdx.x;

    const int blk  = blockIdx.x;        // 1024 = B * 128 * 2
    const int b    = blk >> 8;
    const int rem  = blk & 255;
    const int sblk = rem >> 1;
    const int half = rem & 1;
    const int c0   = half * HALFC;

    for (int i = tid; i < 2048; i += 512) ((float*)shcs)[i] = 0.f;

    for (int i = tid; i < (RNK * HALFC / 4); i += 512) {
        const int r  = i >> 9;
        const int cc = (i & 511) * 4;
        *(float4*)&Vsh[r][cc] = *(const float4*)(V + (size_t)r * IN_ + c0 + cc);
    }
    __syncthreads();

    const int w = tid >> 6, l = tid & 63;
    const int s0 = sblk * 32 + w * 4;
    const float* xb = x + ((size_t)(b * S_ + s0)) * IN_ + c0 + l * 4;

    float acc[4][8];
    #pragma unroll
    for (int row = 0; row < 4; ++row)
        #pragma unroll
        for (int r = 0; r < 8; ++r) acc[row][r] = 0.f;

    float4 xr[4];
    #pragma unroll
    for (int row = 0; row < 4; ++row)
        xr[row] = *(const float4*)(xb + (size_t)row * IN_);

    for (int k = 0; k < NKCH; ++k) {
        float4 xn[4];
        if (k < NKCH - 1) {
            #pragma unroll
            for (int row = 0; row < 4; ++row)
                xn[row] = *(const float4*)(xb + (size_t)row * IN_ + (k + 1) * 256);
        }
        const int col = k * 256 + l * 4;
        float4 vr[8];
        #pragma unroll
        for (int r = 0; r < 8; ++r) vr[r] = *(const float4*)&Vsh[r][col];

        #pragma unroll
        for (int row = 0; row < 4; ++row) {
            #pragma unroll
            for (int r = 0; r < 8; ++r)
                acc[row][r] += xr[row].x * vr[r].x + xr[row].y * vr[r].y
                             + xr[row].z * vr[r].z + xr[row].w * vr[r].w;
        }

        const float c0s = xr[0].x + xr[1].x + xr[2].x + xr[3].x;
        const float c1s = xr[0].y + xr[1].y + xr[2].y + xr[3].y;
        const float c2s = xr[0].z + xr[1].z + xr[2].z + xr[3].z;
        const float c3s = xr[0].w + xr[1].w + xr[2].w + xr[3].w;
        const int q = k * 64 + l;
        atomicAdd(&shcs[0][q], c0s);
        atomicAdd(&shcs[1][q], c1s);
        atomicAdd(&shcs[2][q], c2s);
        atomicAdd(&shcs[3][q], c3s);

        if (k < NKCH - 1) {
            #pragma unroll
            for (int row = 0; row < 4; ++row) xr[row] = xn[row];
        }
    }

    #pragma unroll
    for (int m = 1; m <= 32; m <<= 1)
        #pragma unroll
        for (int row = 0; row < 4; ++row)
            #pragma unroll
            for (int r = 0; r < 8; ++r)
                acc[row][r] += __shfl_xor(acc[row][r], m);

    if (l == 0) {
        float* xo = xvp + (size_t)half * (B_ * S_ * RNK)
                        + ((size_t)(b * S_ + s0)) * RNK;
        #pragma unroll
        for (int row = 0; row < 4; ++row) {
            *(float4*)(xo + row * RNK)     = make_float4(acc[row][0], acc[row][1],
                                                         acc[row][2], acc[row][3]);
            *(float4*)(xo + row * RNK + 4) = make_float4(acc[row][4], acc[row][5],
                                                         acc[row][6], acc[row][7]);
        }
    }

    __syncthreads();
    for (int i = tid; i < 2048; i += 512) {
        const int comp = i >> 9, q = i & 511;
        unsafeAtomicAdd(&colsum[(size_t)b * IN_ + c0 + q * 4 + comp], ((float*)shcs)[i]);
    }
}

// ---------------------------------------------------------------------------
// Kernel R (router only): one 1024-thread block per batch. Computes the 25
// scalar reductions, router softmax, gate, and writes gT[b][64] =
// gate * Lam^T (j-major: gT[j*8+r]). NO OUT_-loop, no P — that contraction
// moved into kD where U is read anyway.
// ---------------------------------------------------------------------------
__global__ __launch_bounds__(1024) void kR(const float* __restrict__ x,
                                           const float* __restrict__ V,
                                           const float* __restrict__ U,
                                           const float* __restrict__ core_pool,
                                           const float* __restrict__ core_keys,
                                           const float* __restrict__ gate_w,
                                           const float* __restrict__ gate_b,
                                           const float* __restrict__ colsum,
                                           float* __restrict__ gT) // [B_][64]
{
    const int b = blockIdx.x, tid = threadIdx.x;
    float nrm2 = 0.f;
    float dotk[K_] = {0.f,0.f,0.f,0.f};
    float kn2[K_]  = {0.f,0.f,0.f,0.f};
    float us[8] = {0.f,0.f,0.f,0.f,0.f,0.f,0.f,0.f};
    float vs[8] = {0.f,0.f,0.f,0.f,0.f,0.f,0.f,0.f};

    const float ms = 0.3f / (float)S_;
    {
        const int c = tid * 4;   // 1024 threads x 4 = 4096 cols, single pass
        const float4 cs = *(const float4*)(colsum + (size_t)b * IN_ + c);
        const float4 xl = *(const float4*)(x + ((size_t)(b * S_ + S_ - 1)) * IN_ + c);
        float4 cen;
        cen.x = 0.7f * xl.x + ms * cs.x;
        cen.y = 0.7f * xl.y + ms * cs.y;
        cen.z = 0.7f * xl.z + ms * cs.z;
        cen.w = 0.7f * xl.w + ms * cs.w;
        nrm2 += cen.x*cen.x + cen.y*cen.y + cen.z*cen.z + cen.w*cen.w;
        #pragma unroll
        for (int k = 0; k < K_; ++k) {
            const float4 ck = *(const float4*)(core_keys + (size_t)k * IN_ + c);
            dotk[k] += cen.x*ck.x + cen.y*ck.y + cen.z*ck.z + cen.w*ck.w;
            kn2[k]  += ck.x*ck.x + ck.y*ck.y + ck.z*ck.z + ck.w*ck.w;
        }
    }
    for (int o = tid; o < OUT_; o += 1024) {
        const float4 a  = *(const float4*)(U + (size_t)o * RNK);
        const float4 b4 = *(const float4*)(U + (size_t)o * RNK + 4);
        us[0]+=a.x;  us[1]+=a.y;  us[2]+=a.z;  us[3]+=a.w;
        us[4]+=b4.x; us[5]+=b4.y; us[6]+=b4.z; us[7]+=b4.w;
    }
    {
        const int c = tid * 4;
        #pragma unroll
        for (int r = 0; r < 8; ++r) {
            const float4 v = *(const float4*)(V + (size_t)r * IN_ + c);
            vs[r] += v.x + v.y + v.z + v.w;
        }
    }

    __shared__ float red[25 * 16];
    __shared__ float res[25];
    float vals[25];
    vals[0] = nrm2;
    #pragma unroll
    for (int k = 0; k < K_; ++k) { vals[1 + k] = dotk[k]; vals[5 + k] = kn2[k]; }
    #pragma unroll
    for (int r = 0; r < 8; ++r) { vals[9 + r] = us[r]; vals[17 + r] = vs[r]; }
    const int wid = tid >> 6, lane = tid & 63;
    #pragma unroll
    for (int i = 0; i < 25; ++i) {
        float v = vals[i];
        #pragma unroll
        for (int m = 32; m >= 1; m >>= 1) v += __shfl_xor(v, m);
        if (lane == 0) red[i * 16 + wid] = v;
    }
    __syncthreads();
    if (tid < 25) {
        float t = 0.f;
        #pragma unroll
        for (int j = 0; j < 16; ++j) t += red[tid * 16 + j];
        res[tid] = t;
    }
    __syncthreads();

    if (tid < 64) {
        const float ncen = fmaxf(sqrtf(res[0]), 1e-8f);
        float lg[K_], mx = -1e30f;
        #pragma unroll
        for (int k = 0; k < K_; ++k) {
            const float nk = fmaxf(sqrtf(res[5 + k]), 1e-8f);
            lg[k] = (res[1 + k] / (ncen * nk)) * 20.0f;   // /TEMP, TEMP=0.05
            mx = fmaxf(mx, lg[k]);
        }
        float wk[K_], se = 0.f;
        #pragma unroll
        for (int k = 0; k < K_; ++k) { wk[k] = expf(lg[k] - mx); se += wk[k]; }
        const float inv_se = 1.f / se;
        float z = gate_b[0];
        #pragma unroll
        for (int r = 0; r < 8; ++r) z += gate_w[r]     * (res[9 + r]  * (1.f / OUT_));
        #pragma unroll
        for (int r = 0; r < 8; ++r) z += gate_w[8 + r] * (res[17 + r] * (1.f / IN_));
        const float gate = 1.f / (1.f + expf(-z));

        float acc = 0.f;
        #pragma unroll
        for (int k = 0; k < K_; ++k) acc += (wk[k] * inv_se) * core_pool[k * 64 + tid];
        gT[b * 64 + tid] = gate * acc;
    }
}

// ---------------------------------------------------------------------------
// Kernel D: out[b,s,o] = sum_j U[o,j] * gT[b,j,:] . (xv0+xv1)[b,s,:].
// P is computed on the fly from U x gT (one-time 512 FMA/thread), then the
// write-bound s-loop with non-temporal stores.
// ---------------------------------------------------------------------------
__global__ __launch_bounds__(256) void kD(const float* __restrict__ U,
                                          const float* __restrict__ gT, // [B_][64]
                                          const float* __restrict__ xv, // [2][B_][S_][RNK]
                                          float* __restrict__ out)
{
    const int blk = blockIdx.x;            // 2048 = B * 256 * 2
    const int b = blk >> 9, rem = blk & 511;
    const int half = rem >> 8, sc = rem & 255;
    const int t = threadIdx.x;
    const int oA = half * 2048 + t * 4;

    __shared__ float Tsh[64];              // Tsh[j*8+r] = gate * Lam[b,j,r]
    if (t < 64) Tsh[t] = gT[b * 64 + t];
    __syncthreads();

    float PA[4][8], PB[4][8];
    #pragma unroll
    for (int u = 0; u < 4; ++u) {
        const float* up = U + (size_t)(oA + u) * RNK;
        const float4 a = *(const float4*)up;
        const float4 c = *(const float4*)(up + 4);
        const float ua[8] = {a.x, a.y, a.z, a.w, c.x, c.y, c.z, c.w};
        const float* uq = up + (size_t)1024 * RNK;
        const float4 d = *(const float4*)uq;
        const float4 e = *(const float4*)(uq + 4);
        const float ub[8] = {d.x, d.y, d.z, d.w, e.x, e.y, e.z, e.w};
        #pragma unroll
        for (int r = 0; r < 8; ++r) {
            float sA = 0.f, sB = 0.f;
            #pragma unroll
            for (int jj = 0; jj < 8; ++jj) {
                sA += ua[jj] * Tsh[jj * 8 + r];
                sB += ub[jj] * Tsh[jj * 8 + r];
            }
            PA[u][r] = sA; PB[u][r] = sB;
        }
    }

    const int srow0 = sc * 16;
    const float* xq0 = xv + ((size_t)(b * S_ + srow0)) * RNK;
    const float* xq1 = xq0 + (size_t)(B_ * S_ * RNK);
    float* op = out + ((size_t)(b * S_ + srow0)) * OUT_ + oA;
    #pragma unroll 4
    for (int row = 0; row < 16; ++row) {
        const float4 xa = *(const float4*)(xq0 + row * RNK);
        const float4 xb = *(const float4*)(xq0 + row * RNK + 4);
        const float4 ya = *(const float4*)(xq1 + row * RNK);
        const float4 yb = *(const float4*)(xq1 + row * RNK + 4);
        const float xr[8] = {xa.x+ya.x, xa.y+ya.y, xa.z+ya.z, xa.w+ya.w,
                             xb.x+yb.x, xb.y+yb.y, xb.z+yb.z, xb.w+yb.w};
        float accA[4], accB[4];
        #pragma unroll
        for (int u = 0; u < 4; ++u) {
            float sA = 0.f, sB = 0.f;
            #pragma unroll
            for (int r = 0; r < 8; ++r) { sA += PA[u][r] * xr[r]; sB += PB[u][r] * xr[r]; }
            accA[u] = sA; accB[u] = sB;
        }
        f4v vA = {accA[0], accA[1], accA[2], accA[3]};
        f4v vB = {accB[0], accB[1], accB[2], accB[3]};
        __builtin_nontemporal_store(vA, (f4v*)(op + (size_t)row * OUT_));
        __builtin_nontemporal_store(vB, (f4v*)(op + (size_t)row * OUT_ + 1024));
    }
}

extern "C" void kernel_launch(void* const* d_in, const int* in_sizes, int n_in,
                              void* d_out, int out_size, void* d_ws, size_t ws_size,
                              hipStream_t stream) {
    const float* x         = (const float*)d_in[0];
    const float* V         = (const float*)d_in[1];
    const float* U         = (const float*)d_in[2];
    const float* core_pool = (const float*)d_in[3];
    const float* core_keys = (const float*)d_in[4];
    const float* gate_w    = (const float*)d_in[5];
    const float* gate_b    = (const float*)d_in[6];
    float* out = (float*)d_out;

    // workspace: colsum [B,IN] + xv partials [2,B,S,8] + gT [B,64]  (~2.1 MB)
    float* colsum = (float*)d_ws;
    float* xv = colsum + (size_t)B_ * IN_;
    float* gT = xv + (size_t)2 * B_ * S_ * RNK;

    zK<<<dim3((B_ * IN_) / 256), dim3(256), 0, stream>>>(colsum);
    kA<<<dim3(1024), dim3(512), 0, stream>>>(x, V, colsum, xv);
    kR<<<dim3(B_), dim3(1024), 0, stream>>>(x, V, U, core_pool, core_keys,
                                            gate_w, gate_b, colsum, gT);
    kD<<<dim3(2048), dim3(256), 0, stream>>>(U, gT, xv, out);
}